// Round 3
// baseline (145.770 us; speedup 1.0000x reference)
//
#include <hip/hip_runtime.h>

// Problem constants (from reference setup_inputs)
#define NBOX 256
#define NC   32
#define ND   64
#define NH   64
#define NW   64
#define CD   16
#define CH   16
#define CW   16
#define NXCD 8
#define HW_  (NH * NW)
#define DHW  (ND * NH * NW)
#define PAD  68            // floats per staged LDS row (64 + 4 pad, 68%32==4)

__global__ __launch_bounds__(256) void CropAndResize3D_89481348645400_kernel(
    const float* __restrict__ image,   // (N, C, D, H, W)
    const float* __restrict__ boxes,   // (NB, 6) = x1,y1,z1,x2,y2,z2
    const int*   __restrict__ box_ind, // (NB,)
    float*       __restrict__ out)     // (NB, C, CD, CH, CW)
{
    // 64 staged rows: r = zc*32 + yo*2 + yc, each 64 floats (+4 pad)
    __shared__ float sh[64 * PAD];     // 17408 B

    // XCD-aware swizzle (kept from R1: FETCH 509->325 MB)
    const int nwg_per_xcd = (NBOX * CD) / NXCD;   // 512
    const int hw  = blockIdx.x;
    const int blk = (hw & (NXCD - 1)) * nwg_per_xcd + (hw >> 3);

    const int b = blk >> 4;            // box index
    const int z = blk & 15;            // crop depth index
    const int t  = threadIdx.x;
    const int ty = t >> 4;             // out-y / stage row-subindex
    const int tx = t & 15;             // out-x / stage float4-group

    const float bx1 = boxes[b * 6 + 0];
    const float by1 = boxes[b * 6 + 1];
    const float bz1 = boxes[b * 6 + 2];
    const float bx2 = boxes[b * 6 + 3];
    const float by2 = boxes[b * 6 + 4];
    const float bz2 = boxes[b * 6 + 5];
    const int   n   = box_ind[b];

    const float zstep = (bz2 - bz1) * 63.0f / 15.0f;
    const float ystep = (by2 - by1) * 63.0f / 15.0f;
    const float xstep = (bx2 - bx1) * 63.0f / 15.0f;

    // z: block-uniform
    const float zc = bz1 * 63.0f + (float)z * zstep;
    const bool  vz = (zc >= 0.0f) && (zc <= 63.0f);
    const float zq = fminf(fmaxf(zc, 0.0f), 63.0f);
    const int   z0 = (int)floorf(zq);
    const int   z1 = min(z0 + 1, ND - 1);
    const float fz = zq - (float)z0;

    // y for this compute thread (row CONTENT is staged; only frac needed here)
    const float ycf = by1 * 63.0f + (float)ty * ystep;
    const bool  vy  = (ycf >= 0.0f) && (ycf <= 63.0f);
    const float yq  = fminf(fmaxf(ycf, 0.0f), 63.0f);
    const float fy  = yq - floorf(yq);

    // x for this compute thread
    const float xcf = bx1 * 63.0f + (float)tx * xstep;
    const bool  vx  = (xcf >= 0.0f) && (xcf <= 63.0f);
    const float xq  = fminf(fmaxf(xcf, 0.0f), 63.0f);
    const int   x0  = (int)floorf(xq);
    const int   x1  = min(x0 + 1, NW - 1);
    const float fx  = xq - (float)x0;

    const bool valid = vz && vy && vx;
    const float gz = 1.0f - fz, gy = 1.0f - fy, gx = 1.0f - fx;

    // ---- stager: this thread fills float4-slot tx of rows r = k*16+ty ----
    // r -> zc = r>>5, yo = (r>>1)&15, yc = r&1  (so yc == ty&1 for all k)
    int soff[4];   // channel-invariant spatial element offsets
    int dst[4];    // LDS float offsets
    #pragma unroll
    for (int k = 0; k < 4; ++k) {
        const int r   = k * 16 + ty;
        const int yo  = (r >> 1) & 15;
        const int yc_ = r & 1;
        const int zs  = (r >> 5) ? z1 : z0;
        const float yco = by1 * 63.0f + (float)yo * ystep;
        const float yqs = fminf(fmaxf(yco, 0.0f), 63.0f);
        const int   ys0 = (int)floorf(yqs);
        const int   ysel = yc_ ? min(ys0 + 1, NH - 1) : ys0;
        soff[k] = zs * HW_ + ysel * NW + tx * 4;
        dst[k]  = r * PAD + tx * 4;
    }

    // compute-side LDS row bases (floats)
    const int r00 = (ty * 2 + 0) * PAD;          // z0, y0
    const int r01 = (ty * 2 + 1) * PAD;          // z0, y1
    const int r10 = (32 + ty * 2 + 0) * PAD;     // z1, y0
    const int r11 = (32 + ty * 2 + 1) * PAD;     // z1, y1

    const float* imgb = image + (size_t)n * (NC * DHW);
    float* op = out + (size_t)b * (NC * CD * CH * CW) + (z * CH + ty) * CW + tx;

    float4 A0, A1, A2, A3, B0, B1, B2, B3;

    #define LOADSET(R0, R1, R2, R3, c)  do {                                   \
        const float* pc_ = imgb + (size_t)(c) * DHW;                           \
        R0 = *(const float4*)(pc_ + soff[0]);                                  \
        R1 = *(const float4*)(pc_ + soff[1]);                                  \
        R2 = *(const float4*)(pc_ + soff[2]);                                  \
        R3 = *(const float4*)(pc_ + soff[3]);                                  \
    } while (0)

    #define WRITESET(R0, R1, R2, R3)  do {                                     \
        *(float4*)(sh + dst[0]) = R0;                                          \
        *(float4*)(sh + dst[1]) = R1;                                          \
        *(float4*)(sh + dst[2]) = R2;                                          \
        *(float4*)(sh + dst[3]) = R3;                                          \
    } while (0)

    #define COMPUTE(c)  do {                                                   \
        const float s000 = sh[r00 + x0], s001 = sh[r00 + x1];                  \
        const float s010 = sh[r01 + x0], s011 = sh[r01 + x1];                  \
        const float s100 = sh[r10 + x0], s101 = sh[r10 + x1];                  \
        const float s110 = sh[r11 + x0], s111 = sh[r11 + x1];                  \
        const float c00 = s000 * gx + s001 * fx;                               \
        const float c01 = s010 * gx + s011 * fx;                               \
        const float c10 = s100 * gx + s101 * fx;                               \
        const float c11 = s110 * gx + s111 * fx;                               \
        const float c0  = c00 * gy + c01 * fy;                                 \
        const float c1  = c10 * gy + c11 * fy;                                 \
        float v = c0 * gz + c1 * fz;                                           \
        v = valid ? v : 0.0f;                                                  \
        __builtin_nontemporal_store(v, op + (c) * (CD * CH * CW));             \
    } while (0)

    // prologue: load channel 0 into A
    LOADSET(A0, A1, A2, A3, 0);

    #pragma unroll 2
    for (int c = 0; c < NC; c += 2) {
        // ---- channel c (regs A) ----
        __syncthreads();                 // readers of previous channel done
        WRITESET(A0, A1, A2, A3);        // (implicit vmcnt wait on A)
        if (c + 1 < NC) LOADSET(B0, B1, B2, B3, c + 1);  // prefetch next
        __syncthreads();                 // staged rows visible
        COMPUTE(c);

        // ---- channel c+1 (regs B) ----
        __syncthreads();
        WRITESET(B0, B1, B2, B3);
        if (c + 2 < NC) LOADSET(A0, A1, A2, A3, c + 2);
        __syncthreads();
        COMPUTE(c + 1);
    }

    #undef LOADSET
    #undef WRITESET
    #undef COMPUTE
}

extern "C" void kernel_launch(void* const* d_in, const int* in_sizes, int n_in,
                              void* d_out, int out_size, void* d_ws, size_t ws_size,
                              hipStream_t stream) {
    const float* image   = (const float*)d_in[0];
    const float* boxes   = (const float*)d_in[1];
    const int*   box_ind = (const int*)d_in[2];
    float*       out     = (float*)d_out;

    const int blocks = NBOX * CD;  // 4096
    CropAndResize3D_89481348645400_kernel<<<blocks, 256, 0, stream>>>(
        image, boxes, box_ind, out);
}

// Round 4
// 132.461 us; speedup vs baseline: 1.1005x; 1.1005x over previous
//
#include <hip/hip_runtime.h>

// Problem constants (from reference setup_inputs)
#define NBOX 256
#define NC   32
#define ND   64
#define NH   64
#define NW   64
#define CD   16
#define CH   16
#define CW   16
#define NXCD 8
#define HW_  (NH * NW)
#define DHW  (ND * NH * NW)
#define CBATCH 4

__global__ __launch_bounds__(256) void CropAndResize3D_89481348645400_kernel(
    const float* __restrict__ image,   // (N, C, D, H, W)
    const float* __restrict__ boxes,   // (NB, 6) = x1,y1,z1,x2,y2,z2
    const int*   __restrict__ box_ind, // (NB,)
    float*       __restrict__ out)     // (NB, C, CD, CH, CW)
{
    // XCD-aware swizzle (R1 win: FETCH 509->325 MB). 4096 % 8 == 0, bijective.
    const int nwg_per_xcd = (NBOX * CD) / NXCD;   // 512
    const int hw  = blockIdx.x;
    const int blk = (hw & (NXCD - 1)) * nwg_per_xcd + (hw >> 3);

    const int b = blk >> 4;           // box index
    const int z = blk & 15;           // crop depth index
    const int t = threadIdx.x;        // 256 threads = 16x16 (y,x)
    const int y = t >> 4;
    const int x = t & 15;

    // boxes layout: [x1, y1, z1, x2, y2, z2]
    const float bx1 = boxes[b * 6 + 0];
    const float by1 = boxes[b * 6 + 1];
    const float bz1 = boxes[b * 6 + 2];
    const float bx2 = boxes[b * 6 + 3];
    const float by2 = boxes[b * 6 + 4];
    const float bz2 = boxes[b * 6 + 5];
    const int   n   = box_ind[b];

    // coords exactly as reference: lo*(L-1) + i * ((hi-lo)*(L-1)/(c-1))
    const float zstep = (bz2 - bz1) * 63.0f / 15.0f;
    const float ystep = (by2 - by1) * 63.0f / 15.0f;
    const float xstep = (bx2 - bx1) * 63.0f / 15.0f;
    const float zc = bz1 * 63.0f + (float)z * zstep;
    const float yc = by1 * 63.0f + (float)y * ystep;
    const float xc = bx1 * 63.0f + (float)x * xstep;

    const bool valid =
        (zc >= 0.0f) && (zc <= 63.0f) &&
        (yc >= 0.0f) && (yc <= 63.0f) &&
        (xc >= 0.0f) && (xc <= 63.0f);

    const float zq = fminf(fmaxf(zc, 0.0f), 63.0f);
    const float yq = fminf(fmaxf(yc, 0.0f), 63.0f);
    const float xq = fminf(fmaxf(xc, 0.0f), 63.0f);
    const int z0 = (int)floorf(zq);
    const int y0 = (int)floorf(yq);
    const int x0 = (int)floorf(xq);
    const int z1 = min(z0 + 1, ND - 1);
    const int y1 = min(y0 + 1, NH - 1);
    const int x1 = min(x0 + 1, NW - 1);
    const float fz = zq - (float)z0;
    const float fy = yq - (float)y0;
    const float fx = xq - (float)x0;
    const float gz = 1.0f - fz, gy = 1.0f - fy, gx = 1.0f - fx;

    const float w000 = gz * gy * gx, w001 = gz * gy * fx;
    const float w010 = gz * fy * gx, w011 = gz * fy * fx;
    const float w100 = fz * gy * gx, w101 = fz * gy * fx;
    const float w110 = fz * fy * gx, w111 = fz * fy * fx;

    // 8 channel-invariant element offsets
    const int e000 = (z0 * NH + y0) * NW + x0;
    const int e001 = (z0 * NH + y0) * NW + x1;
    const int e010 = (z0 * NH + y1) * NW + x0;
    const int e011 = (z0 * NH + y1) * NW + x1;
    const int e100 = (z1 * NH + y0) * NW + x0;
    const int e101 = (z1 * NH + y0) * NW + x1;
    const int e110 = (z1 * NH + y1) * NW + x0;
    const int e111 = (z1 * NH + y1) * NW + x1;

    const float* img = image + (size_t)n * (NC * DHW);
    float* op = out + (size_t)b * (NC * CD * CH * CW) + (z * CH + y) * CW + x;

    // Batch CBATCH channels: issue all 8*CBATCH gathers before consuming ->
    // 32 outstanding loads per thread instead of 8 (latency hiding via ILP).
    #pragma unroll
    for (int cc = 0; cc < NC; cc += CBATCH) {
        float v[CBATCH][8];
        #pragma unroll
        for (int j = 0; j < CBATCH; ++j) {
            const float* p = img + (size_t)(cc + j) * DHW;
            v[j][0] = p[e000]; v[j][1] = p[e001];
            v[j][2] = p[e010]; v[j][3] = p[e011];
            v[j][4] = p[e100]; v[j][5] = p[e101];
            v[j][6] = p[e110]; v[j][7] = p[e111];
        }
        #pragma unroll
        for (int j = 0; j < CBATCH; ++j) {
            float r = v[j][0] * w000 + v[j][1] * w001
                    + v[j][2] * w010 + v[j][3] * w011
                    + v[j][4] * w100 + v[j][5] * w101
                    + v[j][6] * w110 + v[j][7] * w111;
            r = valid ? r : 0.0f;
            __builtin_nontemporal_store(r, op + (cc + j) * (CD * CH * CW));
        }
    }
}

extern "C" void kernel_launch(void* const* d_in, const int* in_sizes, int n_in,
                              void* d_out, int out_size, void* d_ws, size_t ws_size,
                              hipStream_t stream) {
    const float* image   = (const float*)d_in[0];
    const float* boxes   = (const float*)d_in[1];
    const int*   box_ind = (const int*)d_in[2];
    float*       out     = (float*)d_out;

    const int blocks = NBOX * CD;  // 4096
    CropAndResize3D_89481348645400_kernel<<<blocks, 256, 0, stream>>>(
        image, boxes, box_ind, out);
}

// Round 5
// 124.423 us; speedup vs baseline: 1.1716x; 1.0646x over previous
//
#include <hip/hip_runtime.h>

// Problem constants (from reference setup_inputs)
#define NBOX 256
#define NC   32
#define ND   64
#define NH   64
#define NW   64
#define CD   16
#define CH   16
#define CW   16
#define NXCD 8
#define HW_  (NH * NW)
#define DHW  (ND * NH * NW)
#define P    68   // LDS row pitch (floats): 16B-aligned rows (68*4=272=17*16)

__global__ __launch_bounds__(256) void CropAndResize3D_89481348645400_kernel(
    const float* __restrict__ image,   // (N, C, D, H, W)
    const float* __restrict__ boxes,   // (NB, 6) = x1,y1,z1,x2,y2,z2
    const int*   __restrict__ box_ind, // (NB,)
    float*       __restrict__ out)     // (NB, C, CD, CH, CW)
{
    // 64 staged rows per channel buffer: r = zcorner*32 + yo*2 + ycorner
    __shared__ float sh[2][64 * P];    // 2 x 17408 B = 34816 B -> 4 blocks/CU

    // XCD-aware swizzle (R1 win). 4096 % 8 == 0, bijective.
    const int nwg_per_xcd = (NBOX * CD) / NXCD;   // 512
    const int hw  = blockIdx.x;
    const int blk = (hw & (NXCD - 1)) * nwg_per_xcd + (hw >> 3);

    const int b = blk >> 4;            // box index
    const int z = blk & 15;            // crop depth index
    const int t  = threadIdx.x;
    const int ty = t >> 4;             // out-y
    const int tx = t & 15;             // out-x / stage group id

    const float bx1 = boxes[b*6+0], by1 = boxes[b*6+1], bz1 = boxes[b*6+2];
    const float bx2 = boxes[b*6+3], by2 = boxes[b*6+4], bz2 = boxes[b*6+5];
    const int   n   = box_ind[b];

    const float zstep = (bz2 - bz1) * 63.0f / 15.0f;
    const float ystep = (by2 - by1) * 63.0f / 15.0f;
    const float xstep = (bx2 - bx1) * 63.0f / 15.0f;  // >= 0 (boxes sorted)

    // z (block-uniform)
    const float zc = bz1 * 63.0f + (float)z * zstep;
    const bool  vz = (zc >= 0.0f) && (zc <= 63.0f);
    const float zq = fminf(fmaxf(zc, 0.0f), 63.0f);
    const int   z0 = (int)floorf(zq);
    const int   z1 = min(z0 + 1, ND - 1);
    const float fz = zq - (float)z0;

    // y (this thread)
    const float yc = by1 * 63.0f + (float)ty * ystep;
    const bool  vy = (yc >= 0.0f) && (yc <= 63.0f);
    const float yq = fminf(fmaxf(yc, 0.0f), 63.0f);
    const float fy = yq - floorf(yq);

    // x (this thread)
    const float xcf = bx1 * 63.0f + (float)tx * xstep;
    const bool  vx  = (xcf >= 0.0f) && (xcf <= 63.0f);
    const float xq  = fminf(fmaxf(xcf, 0.0f), 63.0f);
    const int   x0  = (int)floorf(xq);
    const int   x1  = min(x0 + 1, NW - 1);
    const float fx  = xq - (float)x0;

    const bool valid = vz && vy && vx;
    const float gz = 1.0f - fz, gy = 1.0f - fy, gx = 1.0f - fx;

    // x-window (block-uniform; xc monotone in tx since xstep >= 0)
    const float xcl = bx1 * 63.0f;
    const float xch = bx1 * 63.0f + 15.0f * xstep;
    const int x0min = (int)floorf(fminf(fmaxf(xcl, 0.0f), 63.0f));
    const int x1max = min((int)floorf(fminf(fmaxf(xch, 0.0f), 63.0f)) + 1, NW - 1);
    const int xlo4  = x0min & ~3;              // 4-aligned window start
    const int G     = ((x1max - xlo4) >> 2) + 1;  // float4 groups, 1..16
    const bool ld   = (tx < G);                // stager lanes

    // stager setup: thread (ty,tx<G) fills group tx of rows r = 16k+ty
    // row r -> zcorner = r>>5, yo = (r>>1)&15, ycorner = r&1
    int soff[4], dst[4];
    #pragma unroll
    for (int k = 0; k < 4; ++k) {
        const int r   = k * 16 + ty;
        const int yo  = (r >> 1) & 15;
        const int yc_ = r & 1;
        const int zs  = (r >> 5) ? z1 : z0;
        const float yco = by1 * 63.0f + (float)yo * ystep;
        const float yqs = fminf(fmaxf(yco, 0.0f), 63.0f);
        const int   ys0 = (int)floorf(yqs);
        const int   ysel = yc_ ? min(ys0 + 1, NH - 1) : ys0;
        soff[k] = (zs * NH + ysel) * NW + xlo4 + tx * 4;  // max idx <= 63: xlo4 4-aligned
        dst[k]  = r * P + tx * 4;
    }

    // compute-side LDS addresses
    const int dx0 = x0 - xlo4;
    const int dx1 = x1 - xlo4;
    const int a00 = (ty * 2 + 0) * P;        // z0,y0
    const int a01 = (ty * 2 + 1) * P;        // z0,y1
    const int a10 = (32 + ty * 2 + 0) * P;   // z1,y0
    const int a11 = (32 + ty * 2 + 1) * P;   // z1,y1

    const float* imgb = image + (size_t)n * (NC * DHW);
    float* op = out + (size_t)b * (NC * CD * CH * CW) + (z * CH + ty) * CW + tx;

    float4 A0, A1, A2, A3, B0, B1, B2, B3;

    #define ISSUE(Ra, Rb, Rc, Rd, c)  do { if (ld) {                         \
        const float* p_ = imgb + (size_t)(c) * DHW;                          \
        Ra = *(const float4*)(p_ + soff[0]);                                 \
        Rb = *(const float4*)(p_ + soff[1]);                                 \
        Rc = *(const float4*)(p_ + soff[2]);                                 \
        Rd = *(const float4*)(p_ + soff[3]); } } while (0)

    #define WRITE(Ra, Rb, Rc, Rd, buf)  do { if (ld) {                       \
        *(float4*)(sh[buf] + dst[0]) = Ra;                                   \
        *(float4*)(sh[buf] + dst[1]) = Rb;                                   \
        *(float4*)(sh[buf] + dst[2]) = Rc;                                   \
        *(float4*)(sh[buf] + dst[3]) = Rd; } } while (0)

    #define COMPUTE(buf, c)  do {                                            \
        const float* S_ = sh[buf];                                           \
        const float s000 = S_[a00 + dx0], s001 = S_[a00 + dx1];              \
        const float s010 = S_[a01 + dx0], s011 = S_[a01 + dx1];              \
        const float s100 = S_[a10 + dx0], s101 = S_[a10 + dx1];              \
        const float s110 = S_[a11 + dx0], s111 = S_[a11 + dx1];              \
        const float c00 = s000 * gx + s001 * fx;                             \
        const float c01 = s010 * gx + s011 * fx;                             \
        const float c10 = s100 * gx + s101 * fx;                             \
        const float c11 = s110 * gx + s111 * fx;                             \
        const float c0  = c00 * gy + c01 * fy;                               \
        const float c1  = c10 * gy + c11 * fy;                               \
        float v = c0 * gz + c1 * fz;                                         \
        v = valid ? v : 0.0f;                                                \
        __builtin_nontemporal_store(v, op + (c) * (CD * CH * CW));           \
    } while (0)

    // prologue: ch0 -> buf0, prefetch ch1 into B
    ISSUE(A0, A1, A2, A3, 0);
    WRITE(A0, A1, A2, A3, 0);      // compiler inserts vmcnt wait
    ISSUE(B0, B1, B2, B3, 1);
    __syncthreads();               // buf0 visible

    // steady state: ONE barrier per channel, 2-deep register pipeline
    for (int c = 0; c < NC; c += 2) {
        // even channel: compute buf0, stage c+1 (regs B) -> buf1
        if (c + 1 < NC) WRITE(B0, B1, B2, B3, 1);
        if (c + 2 < NC) ISSUE(A0, A1, A2, A3, c + 2);
        COMPUTE(0, c);
        __syncthreads();
        // odd channel: compute buf1, stage c+2 (regs A) -> buf0
        if (c + 1 < NC) {
            if (c + 2 < NC) WRITE(A0, A1, A2, A3, 0);
            if (c + 3 < NC) ISSUE(B0, B1, B2, B3, c + 3);
            COMPUTE(1, c + 1);
            __syncthreads();
        }
    }

    #undef ISSUE
    #undef WRITE
    #undef COMPUTE
}

extern "C" void kernel_launch(void* const* d_in, const int* in_sizes, int n_in,
                              void* d_out, int out_size, void* d_ws, size_t ws_size,
                              hipStream_t stream) {
    const float* image   = (const float*)d_in[0];
    const float* boxes   = (const float*)d_in[1];
    const int*   box_ind = (const int*)d_in[2];
    float*       out     = (float*)d_out;

    const int blocks = NBOX * CD;  // 4096
    CropAndResize3D_89481348645400_kernel<<<blocks, 256, 0, stream>>>(
        image, boxes, box_ind, out);
}

// Round 6
// 124.208 us; speedup vs baseline: 1.1736x; 1.0017x over previous
//
#include <hip/hip_runtime.h>
#include <stdint.h>

// Problem constants (from reference setup_inputs)
#define NBOX 256
#define NC   32
#define ND   64
#define NH   64
#define NW   64
#define CD   16
#define CH   16
#define CW   16
#define NXCD 8
#define DHW  (ND * NH * NW)
// LDS: 2 buffers x 64 rows x 64 floats = 32768 B -> exactly 5 blocks/CU (160 KiB)

__global__ __launch_bounds__(256) void CropAndResize3D_89481348645400_kernel(
    const float* __restrict__ image,   // (N, C, D, H, W)
    const float* __restrict__ boxes,   // (NB, 6) = x1,y1,z1,x2,y2,z2
    const int*   __restrict__ box_ind, // (NB,)
    float*       __restrict__ out)     // (NB, C, CD, CH, CW)
{
    __shared__ float sh[2 * 64 * 64];

    // XCD-aware swizzle (R1 win). 4096 % 8 == 0, bijective.
    const int nwg_per_xcd = (NBOX * CD) / NXCD;   // 512
    const int hw  = blockIdx.x;
    const int blk = (hw & (NXCD - 1)) * nwg_per_xcd + (hw >> 3);

    const int b = blk >> 4;            // box index
    const int z = blk & 15;            // crop depth index
    const int t  = threadIdx.x;
    const int ty = t >> 4;             // out-y
    const int tx = t & 15;             // out-x / stage slot id

    const float bx1 = boxes[b*6+0], by1 = boxes[b*6+1], bz1 = boxes[b*6+2];
    const float bx2 = boxes[b*6+3], by2 = boxes[b*6+4], bz2 = boxes[b*6+5];
    const int   n   = box_ind[b];

    const float zstep = (bz2 - bz1) * 63.0f / 15.0f;
    const float ystep = (by2 - by1) * 63.0f / 15.0f;
    const float xstep = (bx2 - bx1) * 63.0f / 15.0f;  // >= 0 (boxes sorted)

    // z (block-uniform)
    const float zc = bz1 * 63.0f + (float)z * zstep;
    const bool  vz = (zc >= 0.0f) && (zc <= 63.0f);
    const float zq = fminf(fmaxf(zc, 0.0f), 63.0f);
    const int   z0 = (int)floorf(zq);
    const int   z1 = min(z0 + 1, ND - 1);
    const float fz = zq - (float)z0;

    // y (this thread)
    const float yc = by1 * 63.0f + (float)ty * ystep;
    const bool  vy = (yc >= 0.0f) && (yc <= 63.0f);
    const float yq = fminf(fmaxf(yc, 0.0f), 63.0f);
    const float fy = yq - floorf(yq);

    // x (this thread)
    const float xcf = bx1 * 63.0f + (float)tx * xstep;
    const bool  vx  = (xcf >= 0.0f) && (xcf <= 63.0f);
    const float xq  = fminf(fmaxf(xcf, 0.0f), 63.0f);
    const int   x0  = (int)floorf(xq);
    const int   x1  = min(x0 + 1, NW - 1);
    const float fx  = xq - (float)x0;

    const bool valid = vz && vy && vx;
    const float gz = 1.0f - fz, gy = 1.0f - fy, gx = 1.0f - fx;

    // x-window (block-uniform; xc monotone in tx since xstep >= 0)
    const float xcl = bx1 * 63.0f;
    const float xch = bx1 * 63.0f + 15.0f * xstep;
    const int x0min = (int)floorf(fminf(fmaxf(xcl, 0.0f), 63.0f));
    const int x1max = min((int)floorf(fminf(fmaxf(xch, 0.0f), 63.0f)) + 1, NW - 1);
    const int xlo4  = x0min & ~3;                  // 4-aligned window start
    const int G     = ((x1max - xlo4) >> 2) + 1;   // float4 groups, 1..16

    // ---- staging (DMA): row r = zc*32 + yo*2 + ycorner, slot s holds global
    // group s ^ (r&7)  [XOR swizzle via pre-swizzled SOURCE, linear LDS dest].
    // Wave layout: lane l -> row base_row + (l>>4), slot l&15  == base + l*16B.
    const int key = ty & 7;                        // == r&7 for r = k*16+ty
    const bool act = ((tx ^ key) < G);             // G active slots per row
    const int sx  = xlo4 + ((tx ^ key) << 2);      // swizzled global x start

    int soff0, soff1, soff2, soff3;
    {
        int tmp[4];
        #pragma unroll
        for (int k = 0; k < 4; ++k) {
            const int r   = k * 16 + ty;
            const int yo  = (r >> 1) & 15;
            const int yc_ = r & 1;
            const int zs  = (r >> 5) ? z1 : z0;
            const float yco = by1 * 63.0f + (float)yo * ystep;
            const float yqs = fminf(fmaxf(yco, 0.0f), 63.0f);
            const int   ys0 = (int)floorf(yqs);
            const int   ysel = yc_ ? min(ys0 + 1, NH - 1) : ys0;
            tmp[k] = (zs * NH + ysel) * NW + sx;
        }
        soff0 = tmp[0]; soff1 = tmp[1]; soff2 = tmp[2]; soff3 = tmp[3];
    }
    // wave-uniform LDS float offsets for the 4 DMA calls
    const int wb    = (ty & ~3) * 64;              // wave base row * 64
    const int ldsb0 = wb;                          // k=0: rows  0+4w..
    const int ldsb1 = wb + 16 * 64;                // k=1
    const int ldsb2 = wb + 32 * 64;                // k=2
    const int ldsb3 = wb + 48 * 64;                // k=3

    // ---- compute-side swizzled LDS read addresses (channel-invariant) ----
    const int dx0 = x0 - xlo4;
    const int dx1 = x1 - xlo4;                     // <= x1max-xlo4 < 4G (staged)
    #define IDX(r, dx) ((r) * 64 + (((((dx) >> 2) ^ ((r) & 7))) << 2) + ((dx) & 3))
    const int a000 = IDX(2*ty    , dx0), a001 = IDX(2*ty    , dx1);
    const int a010 = IDX(2*ty + 1, dx0), a011 = IDX(2*ty + 1, dx1);
    const int a100 = IDX(32+2*ty , dx0), a101 = IDX(32+2*ty , dx1);
    const int a110 = IDX(33+2*ty , dx0), a111 = IDX(33+2*ty , dx1);
    #undef IDX

    const float* imgb = image + (size_t)n * (NC * DHW);
    float* op = out + (size_t)b * (NC * CD * CH * CW) + (z * CH + ty) * CW + tx;

    #define ISSUE(c)  do { if (act) {                                          \
        const float* p_ = imgb + (size_t)(c) * DHW;                            \
        float* l_ = sh + (((c) & 1) << 12);                                    \
        __builtin_amdgcn_global_load_lds(                                      \
            (const __attribute__((address_space(1))) uint32_t*)(p_ + soff0),   \
            (__attribute__((address_space(3))) uint32_t*)(l_ + ldsb0), 16, 0, 0); \
        __builtin_amdgcn_global_load_lds(                                      \
            (const __attribute__((address_space(1))) uint32_t*)(p_ + soff1),   \
            (__attribute__((address_space(3))) uint32_t*)(l_ + ldsb1), 16, 0, 0); \
        __builtin_amdgcn_global_load_lds(                                      \
            (const __attribute__((address_space(1))) uint32_t*)(p_ + soff2),   \
            (__attribute__((address_space(3))) uint32_t*)(l_ + ldsb2), 16, 0, 0); \
        __builtin_amdgcn_global_load_lds(                                      \
            (const __attribute__((address_space(1))) uint32_t*)(p_ + soff3),   \
            (__attribute__((address_space(3))) uint32_t*)(l_ + ldsb3), 16, 0, 0); \
    } } while (0)

    #define COMPUTE(c)  do {                                                   \
        const float* S_ = sh + (((c) & 1) << 12);                              \
        const float s000 = S_[a000], s001 = S_[a001];                          \
        const float s010 = S_[a010], s011 = S_[a011];                          \
        const float s100 = S_[a100], s101 = S_[a101];                          \
        const float s110 = S_[a110], s111 = S_[a111];                          \
        const float c00 = s000 * gx + s001 * fx;                               \
        const float c01 = s010 * gx + s011 * fx;                               \
        const float c10 = s100 * gx + s101 * fx;                               \
        const float c11 = s110 * gx + s111 * fx;                               \
        const float c0  = c00 * gy + c01 * fy;                                 \
        const float c1  = c10 * gy + c11 * fy;                                 \
        float v = c0 * gz + c1 * fz;                                           \
        v = valid ? v : 0.0f;                                                  \
        __builtin_nontemporal_store(v, op + (c) * (CD * CH * CW));             \
    } while (0)

    // prologue: ch0 -> buf0, ch1 -> buf1; wait ch0 (keep ch1 in flight)
    ISSUE(0);
    ISSUE(1);
    asm volatile("s_waitcnt vmcnt(4)" ::: "memory");
    __builtin_amdgcn_s_barrier();
    __builtin_amdgcn_sched_barrier(0);

    #pragma unroll 2
    for (int c = 0; c < NC; ++c) {
        COMPUTE(c);
        if (c + 1 < NC) {
            __builtin_amdgcn_sched_barrier(0);
            __builtin_amdgcn_s_barrier();           // buf[c&1] free for overwrite
            __builtin_amdgcn_sched_barrier(0);
            if (c + 2 < NC) {
                ISSUE(c + 2);                       // -> buf[c&1]
                asm volatile("s_waitcnt vmcnt(4)" ::: "memory");  // drain c+1
            } else {
                asm volatile("s_waitcnt vmcnt(0)" ::: "memory");  // tail drain
            }
            __builtin_amdgcn_sched_barrier(0);
            __builtin_amdgcn_s_barrier();           // all waves' c+1 rows visible
            __builtin_amdgcn_sched_barrier(0);
        }
    }

    #undef ISSUE
    #undef COMPUTE
}

extern "C" void kernel_launch(void* const* d_in, const int* in_sizes, int n_in,
                              void* d_out, int out_size, void* d_ws, size_t ws_size,
                              hipStream_t stream) {
    const float* image   = (const float*)d_in[0];
    const float* boxes   = (const float*)d_in[1];
    const int*   box_ind = (const int*)d_in[2];
    float*       out     = (float*)d_out;

    const int blocks = NBOX * CD;  // 4096
    CropAndResize3D_89481348645400_kernel<<<blocks, 256, 0, stream>>>(
        image, boxes, box_ind, out);
}

// Round 7
// 111.956 us; speedup vs baseline: 1.3020x; 1.1094x over previous
//
#include <hip/hip_runtime.h>
#include <stdint.h>

// Problem constants (from reference setup_inputs)
#define NBOX 256
#define NC   32
#define ND   64
#define NH   64
#define NW   64
#define CD   16
#define CH   16
#define CW   16
#define NXCD 8
#define DHW  (ND * NH * NW)
// LDS: 2 buffers x 64 rows x 64 floats = 32768 B -> 5 blocks/CU

// ---- pre-kernel: stable counting-sort permutation of boxes by box_ind ----
// perm[rank] = original box id; ranks are unique (stable sort) -> bijective.
__global__ __launch_bounds__(NBOX) void CropAndResize3D_perm_kernel(
    const int* __restrict__ box_ind, int* __restrict__ perm)
{
    __shared__ int nsh[NBOX];
    const int t = threadIdx.x;
    nsh[t] = box_ind[t];
    __syncthreads();
    const int n_t = nsh[t];
    int rank = 0;
    #pragma unroll 8
    for (int j = 0; j < NBOX; ++j) {
        const int n_j = nsh[j];
        rank += (n_j < n_t) || (n_j == n_t && j < t);
    }
    perm[rank] = t;
}

__global__ __launch_bounds__(256) void CropAndResize3D_89481348645400_kernel(
    const float* __restrict__ image,   // (N, C, D, H, W)
    const float* __restrict__ boxes,   // (NB, 6) = x1,y1,z1,x2,y2,z2
    const int*   __restrict__ box_ind, // (NB,)
    const int*   __restrict__ perm,    // (NB,) or null -> identity
    float*       __restrict__ out)     // (NB, C, CD, CH, CW)
{
    __shared__ float sh[2 * 64 * 64];

    // XCD-aware swizzle (R1 win). 4096 % 8 == 0, bijective.
    // With image-sorted perm, each XCD gets ~32 boxes of ~one image.
    const int nwg_per_xcd = (NBOX * CD) / NXCD;   // 512
    const int hw  = blockIdx.x;
    const int blk = (hw & (NXCD - 1)) * nwg_per_xcd + (hw >> 3);

    const int slot = blk >> 4;         // logical (sorted) box slot
    const int b = perm ? perm[slot] : slot;  // actual box id
    const int z = blk & 15;            // crop depth index
    const int t  = threadIdx.x;
    const int ty = t >> 4;             // out-y
    const int tx = t & 15;             // out-x / stage slot id

    const float bx1 = boxes[b*6+0], by1 = boxes[b*6+1], bz1 = boxes[b*6+2];
    const float bx2 = boxes[b*6+3], by2 = boxes[b*6+4], bz2 = boxes[b*6+5];
    const int   n   = box_ind[b];

    const float zstep = (bz2 - bz1) * 63.0f / 15.0f;
    const float ystep = (by2 - by1) * 63.0f / 15.0f;
    const float xstep = (bx2 - bx1) * 63.0f / 15.0f;  // >= 0 (boxes sorted)

    // z (block-uniform)
    const float zc = bz1 * 63.0f + (float)z * zstep;
    const bool  vz = (zc >= 0.0f) && (zc <= 63.0f);
    const float zq = fminf(fmaxf(zc, 0.0f), 63.0f);
    const int   z0 = (int)floorf(zq);
    const int   z1 = min(z0 + 1, ND - 1);
    const float fz = zq - (float)z0;

    // y (this thread)
    const float yc = by1 * 63.0f + (float)ty * ystep;
    const bool  vy = (yc >= 0.0f) && (yc <= 63.0f);
    const float yq = fminf(fmaxf(yc, 0.0f), 63.0f);
    const float fy = yq - floorf(yq);

    // x (this thread)
    const float xcf = bx1 * 63.0f + (float)tx * xstep;
    const bool  vx  = (xcf >= 0.0f) && (xcf <= 63.0f);
    const float xq  = fminf(fmaxf(xcf, 0.0f), 63.0f);
    const int   x0  = (int)floorf(xq);
    const int   x1  = min(x0 + 1, NW - 1);
    const float fx  = xq - (float)x0;

    const bool valid = vz && vy && vx;
    const float gz = 1.0f - fz, gy = 1.0f - fy, gx = 1.0f - fx;

    // x-window (block-uniform; xc monotone in tx since xstep >= 0)
    const float xcl = bx1 * 63.0f;
    const float xch = bx1 * 63.0f + 15.0f * xstep;
    const int x0min = (int)floorf(fminf(fmaxf(xcl, 0.0f), 63.0f));
    const int x1max = min((int)floorf(fminf(fmaxf(xch, 0.0f), 63.0f)) + 1, NW - 1);
    const int xlo4  = x0min & ~3;                  // 4-aligned window start
    const int G     = ((x1max - xlo4) >> 2) + 1;   // float4 groups, 1..16

    // staging (DMA): row r = zcorner*32 + yo*2 + ycorner; slot s holds global
    // group s ^ (r&7) [pre-swizzled SOURCE, linear LDS dest per rule #21].
    const int key = ty & 7;                        // == r&7 for r = k*16+ty
    const bool act = ((tx ^ key) < G);             // G active slots per row
    const int sx  = xlo4 + ((tx ^ key) << 2);      // swizzled global x start

    int soff0, soff1, soff2, soff3;
    {
        int tmp[4];
        #pragma unroll
        for (int k = 0; k < 4; ++k) {
            const int r   = k * 16 + ty;
            const int yo  = (r >> 1) & 15;
            const int yc_ = r & 1;
            const int zs  = (r >> 5) ? z1 : z0;
            const float yco = by1 * 63.0f + (float)yo * ystep;
            const float yqs = fminf(fmaxf(yco, 0.0f), 63.0f);
            const int   ys0 = (int)floorf(yqs);
            const int   ysel = yc_ ? min(ys0 + 1, NH - 1) : ys0;
            tmp[k] = (zs * NH + ysel) * NW + sx;
        }
        soff0 = tmp[0]; soff1 = tmp[1]; soff2 = tmp[2]; soff3 = tmp[3];
    }
    // wave-uniform LDS float offsets for the 4 DMA calls
    const int wb    = (ty & ~3) * 64;              // wave base row * 64
    const int ldsb0 = wb;
    const int ldsb1 = wb + 16 * 64;
    const int ldsb2 = wb + 32 * 64;
    const int ldsb3 = wb + 48 * 64;

    // compute-side swizzled LDS read addresses (channel-invariant)
    const int dx0 = x0 - xlo4;
    const int dx1 = x1 - xlo4;
    #define IDX(r, dx) ((r) * 64 + (((((dx) >> 2) ^ ((r) & 7))) << 2) + ((dx) & 3))
    const int a000 = IDX(2*ty    , dx0), a001 = IDX(2*ty    , dx1);
    const int a010 = IDX(2*ty + 1, dx0), a011 = IDX(2*ty + 1, dx1);
    const int a100 = IDX(32+2*ty , dx0), a101 = IDX(32+2*ty , dx1);
    const int a110 = IDX(33+2*ty , dx0), a111 = IDX(33+2*ty , dx1);
    #undef IDX

    const float* imgb = image + (size_t)n * (NC * DHW);
    float* op = out + (size_t)b * (NC * CD * CH * CW) + (z * CH + ty) * CW + tx;

    #define ISSUE(c)  do { if (act) {                                          \
        const float* p_ = imgb + (size_t)(c) * DHW;                            \
        float* l_ = sh + (((c) & 1) << 12);                                    \
        __builtin_amdgcn_global_load_lds(                                      \
            (const __attribute__((address_space(1))) uint32_t*)(p_ + soff0),   \
            (__attribute__((address_space(3))) uint32_t*)(l_ + ldsb0), 16, 0, 0); \
        __builtin_amdgcn_global_load_lds(                                      \
            (const __attribute__((address_space(1))) uint32_t*)(p_ + soff1),   \
            (__attribute__((address_space(3))) uint32_t*)(l_ + ldsb1), 16, 0, 0); \
        __builtin_amdgcn_global_load_lds(                                      \
            (const __attribute__((address_space(1))) uint32_t*)(p_ + soff2),   \
            (__attribute__((address_space(3))) uint32_t*)(l_ + ldsb2), 16, 0, 0); \
        __builtin_amdgcn_global_load_lds(                                      \
            (const __attribute__((address_space(1))) uint32_t*)(p_ + soff3),   \
            (__attribute__((address_space(3))) uint32_t*)(l_ + ldsb3), 16, 0, 0); \
    } } while (0)

    #define COMPUTE(c)  do {                                                   \
        const float* S_ = sh + (((c) & 1) << 12);                              \
        const float s000 = S_[a000], s001 = S_[a001];                          \
        const float s010 = S_[a010], s011 = S_[a011];                          \
        const float s100 = S_[a100], s101 = S_[a101];                          \
        const float s110 = S_[a110], s111 = S_[a111];                          \
        const float c00 = s000 * gx + s001 * fx;                               \
        const float c01 = s010 * gx + s011 * fx;                               \
        const float c10 = s100 * gx + s101 * fx;                               \
        const float c11 = s110 * gx + s111 * fx;                               \
        const float c0  = c00 * gy + c01 * fy;                                 \
        const float c1  = c10 * gy + c11 * fy;                                 \
        float v = c0 * gz + c1 * fz;                                           \
        v = valid ? v : 0.0f;                                                  \
        __builtin_nontemporal_store(v, op + (c) * (CD * CH * CW));             \
    } while (0)

    // prologue: ch0 -> buf0, ch1 -> buf1; wait ch0 (keep ch1 in flight)
    ISSUE(0);
    ISSUE(1);
    asm volatile("s_waitcnt vmcnt(4)" ::: "memory");
    __builtin_amdgcn_s_barrier();
    __builtin_amdgcn_sched_barrier(0);

    #pragma unroll 2
    for (int c = 0; c < NC; ++c) {
        COMPUTE(c);
        if (c + 1 < NC) {
            __builtin_amdgcn_sched_barrier(0);
            __builtin_amdgcn_s_barrier();           // buf[c&1] free for overwrite
            __builtin_amdgcn_sched_barrier(0);
            if (c + 2 < NC) {
                ISSUE(c + 2);                       // -> buf[c&1]
                asm volatile("s_waitcnt vmcnt(4)" ::: "memory");  // drain c+1
            } else {
                asm volatile("s_waitcnt vmcnt(0)" ::: "memory");  // tail drain
            }
            __builtin_amdgcn_sched_barrier(0);
            __builtin_amdgcn_s_barrier();           // all waves' c+1 rows visible
            __builtin_amdgcn_sched_barrier(0);
        }
    }

    #undef ISSUE
    #undef COMPUTE
}

extern "C" void kernel_launch(void* const* d_in, const int* in_sizes, int n_in,
                              void* d_out, int out_size, void* d_ws, size_t ws_size,
                              hipStream_t stream) {
    const float* image   = (const float*)d_in[0];
    const float* boxes   = (const float*)d_in[1];
    const int*   box_ind = (const int*)d_in[2];
    float*       out     = (float*)d_out;

    int* perm = nullptr;
    if (ws_size >= NBOX * sizeof(int)) {
        perm = (int*)d_ws;
        CropAndResize3D_perm_kernel<<<1, NBOX, 0, stream>>>(box_ind, perm);
    }

    const int blocks = NBOX * CD;  // 4096
    CropAndResize3D_89481348645400_kernel<<<blocks, 256, 0, stream>>>(
        image, boxes, box_ind, perm, out);
}